// Round 1
// baseline (687.551 us; speedup 1.0000x reference)
//
#include <hip/hip_runtime.h>

typedef __bf16 bf16;
typedef __attribute__((ext_vector_type(8))) __bf16 bf16x8;
typedef __attribute__((ext_vector_type(4))) float f32x4;
typedef __attribute__((ext_vector_type(4))) int int4v;

#define SEQ 4096
#define D_IN 2048
#define NHEADS 16
#define MLA_SCALE 0.08838834764831843f
#define RMS_EPS 1e-6f

// ---------------------------------------------------------------- conversions
__global__ __launch_bounds__(256) void f32_to_bf16_kernel(
    const float* __restrict__ in, bf16* __restrict__ out, int n) {
    int i = (blockIdx.x * 256 + threadIdx.x) * 4;
    int stride = gridDim.x * 256 * 4;
    for (; i < n; i += stride) {
        float4 v = *reinterpret_cast<const float4*>(in + i);
        bf16 o[4];
        o[0] = (bf16)v.x; o[1] = (bf16)v.y; o[2] = (bf16)v.z; o[3] = (bf16)v.w;
        *reinterpret_cast<uint2*>(out + i) = *reinterpret_cast<uint2*>(o);
    }
}

// ---------------------------------------------------------------- generic GEMM
// C[M,N] = A[M,K](bf16,row-major) * B[N,K](bf16,row-major)^T
// 128x128 tile, BK=32, 4 waves (2x2 of 64x64), single-buffered padded LDS.
template<bool BF16_OUT>
__global__ __launch_bounds__(256) void gemm_bt_kernel(
    const bf16* __restrict__ A, const bf16* __restrict__ B, void* __restrict__ Cout,
    int M, int N, int K) {
    const int LDS_STRIDE = 40; // 32 + 8 pad (bf16 elems)
    __shared__ bf16 Al[128 * 40];
    __shared__ bf16 Bl[128 * 40];
    int tid  = threadIdx.x;
    int lane = tid & 63;
    int wid  = tid >> 6;
    int wr = wid >> 1, wc = wid & 1;
    int m0 = blockIdx.y * 128;
    int n0 = blockIdx.x * 128;
    int l15 = lane & 15;
    int g   = lane >> 4;

    int srow = tid >> 1;            // 0..127
    int soff = (tid & 1) * 16;      // bf16 offset within 32-wide row (two 16B segs)

    f32x4 acc[4][4] = {};

    for (int k0 = 0; k0 < K; k0 += 32) {
        __syncthreads();
        {
            const bf16* srcA = A + (size_t)(m0 + srow) * K + k0 + soff;
            int4v a0 = *reinterpret_cast<const int4v*>(srcA);
            int4v a1 = *reinterpret_cast<const int4v*>(srcA + 8);
            *reinterpret_cast<int4v*>(&Al[srow * LDS_STRIDE + soff])     = a0;
            *reinterpret_cast<int4v*>(&Al[srow * LDS_STRIDE + soff + 8]) = a1;
            int brow = n0 + srow; if (brow >= N) brow = N - 1;
            const bf16* srcB = B + (size_t)brow * K + k0 + soff;
            int4v b0 = *reinterpret_cast<const int4v*>(srcB);
            int4v b1 = *reinterpret_cast<const int4v*>(srcB + 8);
            *reinterpret_cast<int4v*>(&Bl[srow * LDS_STRIDE + soff])     = b0;
            *reinterpret_cast<int4v*>(&Bl[srow * LDS_STRIDE + soff + 8]) = b1;
        }
        __syncthreads();
        bf16x8 af[4], bfv[4];
        #pragma unroll
        for (int mt = 0; mt < 4; mt++)
            af[mt] = *reinterpret_cast<const bf16x8*>(&Al[(wr*64 + mt*16 + l15) * LDS_STRIDE + g*8]);
        #pragma unroll
        for (int nt = 0; nt < 4; nt++)
            bfv[nt] = *reinterpret_cast<const bf16x8*>(&Bl[(wc*64 + nt*16 + l15) * LDS_STRIDE + g*8]);
        #pragma unroll
        for (int mt = 0; mt < 4; mt++)
            #pragma unroll
            for (int nt = 0; nt < 4; nt++)
                acc[mt][nt] = __builtin_amdgcn_mfma_f32_16x16x32_bf16(af[mt], bfv[nt], acc[mt][nt], 0, 0, 0);
    }

    #pragma unroll
    for (int mt = 0; mt < 4; mt++) {
        #pragma unroll
        for (int nt = 0; nt < 4; nt++) {
            int col = n0 + wc*64 + nt*16 + l15;
            if (col < N) {
                #pragma unroll
                for (int r = 0; r < 4; r++) {
                    int row = m0 + wr*64 + mt*16 + g*4 + r;
                    if (BF16_OUT)
                        ((bf16*)Cout)[(size_t)row * N + col] = (bf16)acc[mt][nt][r];
                    else
                        ((float*)Cout)[(size_t)row * N + col] = acc[mt][nt][r];
                }
            }
        }
    }
}

// ---------------------------------------------------------------- q prep (rope + scale, in place)
__global__ __launch_bounds__(256) void prep_q_kernel(
    bf16* __restrict__ q, const float* __restrict__ cosb, const float* __restrict__ sinb) {
    int s = blockIdx.x;
    int t = threadIdx.x;
    bf16* p = q + (size_t)s * 2048 + t * 8;
    bf16x8 v = *reinterpret_cast<bf16x8*>(p);
    float f[8];
    #pragma unroll
    for (int j = 0; j < 8; j++) f[j] = (float)v[j];
    int d0 = (t & 15) * 8;
    if (d0 >= 64) {
        int ib = (d0 - 64) >> 1;
        #pragma unroll
        for (int pr = 0; pr < 4; pr++) {
            float c  = cosb[s * 32 + ib + pr];
            float sn = sinb[s * 32 + ib + pr];
            float xe = f[pr*2], xo = f[pr*2 + 1];
            f[pr*2]     = xe * c - xo * sn;
            f[pr*2 + 1] = xe * sn + xo * c;
        }
    }
    #pragma unroll
    for (int j = 0; j < 8; j++) v[j] = (bf16)(f[j] * MLA_SCALE);
    *reinterpret_cast<bf16x8*>(p) = v;
}

// ---------------------------------------------------------------- kv prep (rmsnorm + k_pe rope)
__global__ __launch_bounds__(256) void prep_kv_kernel(
    const bf16* __restrict__ kvfull, const float* __restrict__ w,
    const float* __restrict__ cosb, const float* __restrict__ sinb,
    bf16* __restrict__ kvnorm, bf16* __restrict__ kpe) {
    __shared__ float red[4];
    int s = blockIdx.x;
    int t = threadIdx.x;
    const bf16* src = kvfull + (size_t)s * 1088;
    float f[4];
    {
        uint2 raw = *reinterpret_cast<const uint2*>(src + t * 4);
        bf16* vb = reinterpret_cast<bf16*>(&raw);
        float ss = 0.f;
        #pragma unroll
        for (int j = 0; j < 4; j++) { f[j] = (float)vb[j]; ss += f[j] * f[j]; }
        #pragma unroll
        for (int m = 1; m < 64; m <<= 1) ss += __shfl_xor(ss, m);
        if ((t & 63) == 0) red[t >> 6] = ss;
    }
    __syncthreads();
    float tot = red[0] + red[1] + red[2] + red[3];
    float rms = rsqrtf(tot * (1.0f / 1024.0f) + RMS_EPS);
    bf16 o[4];
    #pragma unroll
    for (int j = 0; j < 4; j++) o[j] = (bf16)(f[j] * rms * w[t*4 + j]);
    *reinterpret_cast<uint2*>(kvnorm + (size_t)s * 1024 + t * 4) = *reinterpret_cast<uint2*>(o);
    if (t < 16) {
        float e[4];
        #pragma unroll
        for (int j = 0; j < 4; j++) e[j] = (float)src[1024 + t*4 + j];
        int ib = t * 2;
        float c0 = cosb[s*32 + ib],     s0 = sinb[s*32 + ib];
        float c1 = cosb[s*32 + ib + 1], s1 = sinb[s*32 + ib + 1];
        bf16 ko[4];
        ko[0] = (bf16)(e[0]*c0 - e[1]*s0);
        ko[1] = (bf16)(e[0]*s0 + e[1]*c0);
        ko[2] = (bf16)(e[2]*c1 - e[3]*s1);
        ko[3] = (bf16)(e[2]*s1 + e[3]*c1);
        *reinterpret_cast<uint2*>(kpe + (size_t)s * 64 + t * 4) = *reinterpret_cast<uint2*>(ko);
    }
}

// ---------------------------------------------------------------- build Vt[h][128][4096]
__global__ __launch_bounds__(256) void build_vt_kernel(
    const bf16* __restrict__ kvb, bf16* __restrict__ vt) {
    const int LT = 130; // odd-dword stride -> conflict-free column reads
    __shared__ bf16 lt[64 * 130];
    int h  = blockIdx.y;
    int s0 = blockIdx.x * 64;
    int t  = threadIdx.x;
    {
        int row = t >> 2;            // 0..63
        int d0  = (t & 3) * 32;      // 32 bf16 = 64B per thread
        const bf16* src = kvb + (size_t)(s0 + row) * 3072 + h * 192 + 64 + d0;
        int4v v0 = *reinterpret_cast<const int4v*>(src);
        int4v v1 = *reinterpret_cast<const int4v*>(src + 8);
        int4v v2 = *reinterpret_cast<const int4v*>(src + 16);
        int4v v3 = *reinterpret_cast<const int4v*>(src + 24);
        int* dst = reinterpret_cast<int*>(&lt[row * LT + d0]); // 4B aligned
        int* s0p = reinterpret_cast<int*>(&v0); int* s1p = reinterpret_cast<int*>(&v1);
        int* s2p = reinterpret_cast<int*>(&v2); int* s3p = reinterpret_cast<int*>(&v3);
        #pragma unroll
        for (int j = 0; j < 4; j++) { dst[j] = s0p[j]; dst[4+j] = s1p[j]; dst[8+j] = s2p[j]; dst[12+j] = s3p[j]; }
    }
    __syncthreads();
    int ss = t & 63;
    int db = t >> 6;
    bf16* out = vt + (size_t)h * 128 * 4096 + s0 + ss;
    #pragma unroll
    for (int dd = db; dd < 128; dd += 4)
        out[(size_t)dd * 4096] = lt[ss * LT + dd];
}

// ---------------------------------------------------------------- flash attention
__global__ __launch_bounds__(256) void attn_kernel(
    const bf16* __restrict__ q,     // [4096][2048]  (roped, *SCALE)
    const bf16* __restrict__ kvb,   // [4096][3072]
    const bf16* __restrict__ kpe,   // [4096][64]
    const bf16* __restrict__ vt,    // [16][128][4096]
    bf16* __restrict__ attn) {      // [4096][2048]
    const int LKS = 136, LVS = 40, LPS = 40;
    __shared__ bf16 Kl[32 * 136];
    __shared__ bf16 Vl[128 * 40];
    __shared__ bf16 Pl[4][16 * 40];

    int h  = blockIdx.y;
    int q0 = blockIdx.x * 64;
    int t  = threadIdx.x;
    int lane = t & 63;
    int w  = t >> 6;
    int l15 = lane & 15;
    int g   = lane >> 4;
    int qrow = q0 + w * 16;

    bf16x8 qf[4];
    {
        const bf16* qp = q + (size_t)(qrow + l15) * 2048 + h * 128 + g * 8;
        #pragma unroll
        for (int c = 0; c < 4; c++) qf[c] = *reinterpret_cast<const bf16x8*>(qp + c * 32);
    }

    f32x4 o[8] = {};
    float mrow[4], lrow[4];
    #pragma unroll
    for (int r = 0; r < 4; r++) { mrow[r] = -3e38f; lrow[r] = 0.f; }

    int nchunks = (q0 + 64) >> 5;
    for (int jc = 0; jc < nchunks; ++jc) {
        int j0 = jc * 32;
        __syncthreads();
        { // stage K chunk [32][128]: k_nope from kvb, k_pe from kpe
            int row = t >> 3;
            int d0  = (t & 7) * 16;
            const bf16* src = (d0 < 64)
                ? kvb + (size_t)(j0 + row) * 3072 + h * 192 + d0
                : kpe + (size_t)(j0 + row) * 64 + (d0 - 64);
            int4v v0 = *reinterpret_cast<const int4v*>(src);
            int4v v1 = *reinterpret_cast<const int4v*>(src + 8);
            *reinterpret_cast<int4v*>(&Kl[row * LKS + d0])     = v0;
            *reinterpret_cast<int4v*>(&Kl[row * LKS + d0 + 8]) = v1;
        }
        { // stage Vt chunk [128][32]
            int drow = t >> 1;
            int joff = (t & 1) * 16;
            const bf16* src = vt + (size_t)h * 524288 + (size_t)drow * 4096 + j0 + joff;
            int4v v0 = *reinterpret_cast<const int4v*>(src);
            int4v v1 = *reinterpret_cast<const int4v*>(src + 8);
            *reinterpret_cast<int4v*>(&Vl[drow * LVS + joff])     = v0;
            *reinterpret_cast<int4v*>(&Vl[drow * LVS + joff + 8]) = v1;
        }
        __syncthreads();
        if (j0 <= qrow + 15) {
            f32x4 sfr[2] = {};
            #pragma unroll
            for (int sub = 0; sub < 2; ++sub)
                #pragma unroll
                for (int c = 0; c < 4; c++) {
                    bf16x8 kf = *reinterpret_cast<const bf16x8*>(&Kl[(sub*16 + l15) * LKS + c*32 + g*8]);
                    sfr[sub] = __builtin_amdgcn_mfma_f32_16x16x32_bf16(qf[c], kf, sfr[sub], 0, 0, 0);
                }
            float sfac[4];
            #pragma unroll
            for (int r = 0; r < 4; r++) {
                int i = qrow + g*4 + r;
                #pragma unroll
                for (int sub = 0; sub < 2; sub++) {
                    int j = j0 + sub*16 + l15;
                    if (j > i) sfr[sub][r] = -3e38f;
                }
                float mx = fmaxf(sfr[0][r], sfr[1][r]);
                #pragma unroll
                for (int m = 1; m < 16; m <<= 1) mx = fmaxf(mx, __shfl_xor(mx, m));
                float mnew = fmaxf(mrow[r], mx);
                sfac[r] = __expf(mrow[r] - mnew);
                mrow[r] = mnew;
                float p0 = __expf(sfr[0][r] - mnew);
                float p1 = __expf(sfr[1][r] - mnew);
                sfr[0][r] = p0; sfr[1][r] = p1;
                float ps = p0 + p1;
                #pragma unroll
                for (int m = 1; m < 16; m <<= 1) ps += __shfl_xor(ps, m);
                lrow[r] = lrow[r] * sfac[r] + ps;
            }
            #pragma unroll
            for (int dt = 0; dt < 8; dt++)
                #pragma unroll
                for (int r = 0; r < 4; r++) o[dt][r] *= sfac[r];
            #pragma unroll
            for (int sub = 0; sub < 2; ++sub)
                #pragma unroll
                for (int r = 0; r < 4; r++)
                    Pl[w][(g*4 + r) * LPS + sub*16 + l15] = (bf16)sfr[sub][r];
            bf16x8 pf = *reinterpret_cast<const bf16x8*>(&Pl[w][l15 * LPS + g * 8]);
            #pragma unroll
            for (int dt = 0; dt < 8; dt++) {
                bf16x8 vf = *reinterpret_cast<const bf16x8*>(&Vl[(dt*16 + l15) * LVS + g * 8]);
                o[dt] = __builtin_amdgcn_mfma_f32_16x16x32_bf16(pf, vf, o[dt], 0, 0, 0);
            }
        }
    }
    #pragma unroll
    for (int dt = 0; dt < 8; dt++) {
        #pragma unroll
        for (int r = 0; r < 4; r++) {
            int i = qrow + g*4 + r;
            float val = o[dt][r] / lrow[r];
            attn[(size_t)i * 2048 + h * 128 + dt*16 + l15] = (bf16)val;
        }
    }
}

// ---------------------------------------------------------------- launch
extern "C" void kernel_launch(void* const* d_in, const int* in_sizes, int n_in,
                              void* d_out, int out_size, void* d_ws, size_t ws_size,
                              hipStream_t stream) {
    const float* x    = (const float*)d_in[0];
    const float* cosb = (const float*)d_in[1];
    const float* sinb = (const float*)d_in[2];
    // d_in[3] = mask (unused: causal, start_pos=0)
    const float* wq   = (const float*)d_in[4];
    const float* wkva = (const float*)d_in[5];
    const float* kvw  = (const float*)d_in[6];
    const float* wkvb = (const float*)d_in[7];
    const float* wo   = (const float*)d_in[8];
    // d_in[9] = start_pos (0)

    char* ws = (char*)d_ws;
    bf16* x_bf    = (bf16*)(ws + 0);          // 16.7MB; later reused as kvnorm, then attn
    bf16* kvnorm  = (bf16*)(ws + 0);
    bf16* attn    = (bf16*)(ws + 0);
    bf16* wq_bf   = (bf16*)(ws + 16777216);
    bf16* wkva_bf = (bf16*)(ws + 25165824);
    bf16* wkvb_bf = (bf16*)(ws + 29622272);
    bf16* wo_bf   = (bf16*)(ws + 35913728);
    bf16* q_bf    = (bf16*)(ws + 44302336);
    bf16* kvfull  = (bf16*)(ws + 61079552);
    bf16* kpe     = (bf16*)(ws + 69992448);
    bf16* kvb     = (bf16*)(ws + 70516736);
    bf16* vt      = (bf16*)(ws + 95682560);
    // total: 112459776 bytes

    f32_to_bf16_kernel<<<dim3(512), dim3(256), 0, stream>>>(x,    x_bf,    4096*2048);
    f32_to_bf16_kernel<<<dim3(512), dim3(256), 0, stream>>>(wq,   wq_bf,   2048*2048);
    f32_to_bf16_kernel<<<dim3(512), dim3(256), 0, stream>>>(wkva, wkva_bf, 1088*2048);
    f32_to_bf16_kernel<<<dim3(512), dim3(256), 0, stream>>>(wkvb, wkvb_bf, 3072*1024);
    f32_to_bf16_kernel<<<dim3(512), dim3(256), 0, stream>>>(wo,   wo_bf,   2048*2048);

    gemm_bt_kernel<true><<<dim3(16, 32), dim3(256), 0, stream>>>(x_bf, wq_bf,   q_bf,   4096, 2048, 2048);
    gemm_bt_kernel<true><<<dim3(9,  32), dim3(256), 0, stream>>>(x_bf, wkva_bf, kvfull, 4096, 1088, 2048);

    prep_q_kernel <<<dim3(4096), dim3(256), 0, stream>>>(q_bf, cosb, sinb);
    prep_kv_kernel<<<dim3(4096), dim3(256), 0, stream>>>(kvfull, kvw, cosb, sinb, kvnorm, kpe);

    gemm_bt_kernel<true><<<dim3(24, 32), dim3(256), 0, stream>>>(kvnorm, wkvb_bf, kvb, 4096, 3072, 1024);

    build_vt_kernel<<<dim3(64, 16), dim3(256), 0, stream>>>(kvb, vt);

    attn_kernel<<<dim3(64, 16), dim3(256), 0, stream>>>(q_bf, kvb, kpe, vt, attn);

    gemm_bt_kernel<false><<<dim3(16, 32), dim3(256), 0, stream>>>(attn, wo_bf, (float*)d_out, 4096, 2048, 2048);
}